// Round 11
// baseline (1327.995 us; speedup 1.0000x reference)
//
#include <hip/hip_runtime.h>
#include <hip/hip_fp16.h>

// RNN_16492674416646: h_t = tanh(x_t W_ih^T + b_ih + b_hh + h_{t-1} W_hh^T),
// out_t = h_t W_out^T + b_out. T=2048, B=128, IN=2, H=200, OUT=1, fp32.
//
// R23 = R19 (best: 1010 us) + SIMD equalization. Falsified so far: LDS-read
// count (R22: 91->52 reads = +5%), MFMA count (R21: -4 MFMA/SIMD0 = null),
// drains-on-tile-waves (R19 fix), bookkeeping VALU (R19 fix). Remaining
// mechanism: under w%4 wave->SIMD mapping, R19's SIMD0 hosts waves
// {0,4,8,12} = ALL tile waves: 28 MFMA/step (vs 21) AND no aux wave to
// fill the ~120cy post-barrier read-latency bubble. R23:
//  - NT=12 MFMA tiles (cols 0..191): every SIMD gets exactly 3 tile waves.
//  - cols 192..199: waves 14/15 compute them as a DPP-reduce VALU dot
//    (4 cols each, h = hi+lo, fp16-rounded C2L-scaled weights): ~350cy
//    path, off the MFMA pipe, fills SIMD2/3's bubble.
//  - drains: w12 (even t) / w13 (odd t) -> fills SIMD0/1's bubble.
//    Flush: w13 at rp==0 (its idle parity).
// Under a w/4 mapping this degenerates to ~R19 (not worse). Numerics:
// tail cols computed in fp32 from the same fp16-rounded scaled weights,
// h hi+lo (>= MFMA path precision): absmax 0.0078125 expected unchanged.

typedef short s8v __attribute__((ext_vector_type(8)));   // 8 x fp16 bits
typedef short s4v __attribute__((ext_vector_type(4)));   // 4 x fp16 bits
typedef float f4v __attribute__((ext_vector_type(4)));

static constexpr int T = 2048;
static constexpr int B = 128;
static constexpr int H = 200;
static constexpr int NTHR = 1024;  // 16 waves
static constexpr int NT  = 12;     // MFMA n-tiles of 16 (cols 0..191)
static constexpr int KT  = 7;      // k-tiles of 32 (224 padded)
static constexpr int HP  = 224;    // padded H
static constexpr int RS  = 8;      // ring slots; T % RS == 0
static constexpr float C2L = 2.8853900817779268f;  // 2*log2(e)

__device__ __forceinline__ unsigned short f2h(float f) {
    const __half h = __float2half_rn(f);
    return *(const unsigned short*)&h;
}
__device__ __forceinline__ float h2f(unsigned short u) {
    const __half h = *(const __half*)&u;
    return __half2float(h);
}
// VALU-only cross-lane add (DPP); CTRL is a compile-time literal.
template <int CTRL>
__device__ __forceinline__ float dpp_add(float v) {
    const int i = __builtin_bit_cast(int, v);
    const int p = __builtin_amdgcn_update_dpp(0, i, CTRL, 0xF, 0xF, false);
    return v + __builtin_bit_cast(float, p);
}
__device__ __forceinline__ float rlane(float v, int l) {
    return __builtin_bit_cast(float,
        __builtin_amdgcn_readlane(__builtin_bit_cast(int, v), l));
}

__global__ __attribute__((amdgpu_flat_work_group_size(NTHR, NTHR),
                          amdgpu_waves_per_eu(4, 4)))
void rnn_fused(const float* __restrict__ x,     // [T,B,2]
               const float* __restrict__ W_ih,  // [H,2]
               const float* __restrict__ W_hh,  // [H,H]
               const float* __restrict__ b_ih,  // [H]
               const float* __restrict__ b_hh,  // [H]
               const float* __restrict__ W_out, // [1,H]
               const float* __restrict__ b_out, // [1]
               float* __restrict__ out)         // [T,B]
{
    const int b    = blockIdx.x;
    const int tid  = threadIdx.x;
    const int w    = tid >> 6;       // wave id 0..15
    const int lane = tid & 63;
    const int m    = lane & 15;      // A-row sel / B-col / D-col
    const int q    = lane >> 4;      // k-quad

    const bool hasT   = (w < NT);    // 12 tile waves
    const bool isTail = (w >= 14);   // w14: cols 192..195, w15: 196..199
    const int  nA   = 16 * w + m;    // tile wave col (< 192 < H always)
    const bool colv = hasT;

    __shared__ __align__(16) unsigned short ring[RS][2][HP];  // 7 KiB
    __shared__ __align__(16) float xs[2 * T];                 // 16 KiB
    __shared__ __align__(16) float obuf[128];                 // out staging

    for (int i = tid; i < RS * 2 * HP; i += NTHR) (&ring[0][0][0])[i] = 0;
    for (int idx = tid; idx < T; idx += NTHR) {
        const float2 v = *(const float2*)(x + (size_t)idx * (B * 2) + 2 * b);
        xs[2 * idx] = v.x; xs[2 * idx + 1] = v.y;
    }

    // --- loop-invariant B-fragment (fp16), C2L-scaled ---
    s8v BA[KT];
#pragma unroll
    for (int kt = 0; kt < KT; ++kt) {
        s8v ba{};
        if (colv) {
#pragma unroll
            for (int j = 0; j < 8; ++j) {
                const int ks = 32 * kt + 8 * q + j;
                ba[j] = (short)((ks < H) ? f2h(C2L * W_hh[nA * H + ks])
                                         : (unsigned short)0);
            }
        }
        BA[kt] = ba;
    }

    // --- tile epilogue constants (q==0 lanes own col nA), C2L-scaled ---
    const float wxA0 = colv ? (C2L * W_ih[nA * 2])     : 0.f;
    const float wxA1 = colv ? (C2L * W_ih[nA * 2 + 1]) : 0.f;
    const float bA   = colv ? (C2L * (b_ih[nA] + b_hh[nA])) : 0.f;

    // --- tail-wave constants: 4 cols = cb..cb+3; lane covers k c4..c4+3 ---
    const int c4 = 4 * lane;
    float tw0[4] = {0,0,0,0}, tw1[4] = {0,0,0,0};
    float tw2[4] = {0,0,0,0}, tw3[4] = {0,0,0,0};
    float twx0 = 0.f, twx1 = 0.f, tbA = 0.f;
    if (isTail) {
        const int cb = 192 + 4 * (w - 14);
#pragma unroll
        for (int j = 0; j < 4; ++j) {
            const int k = c4 + j;
            if (lane < 56 && k < H) {   // same fp16-rounded scaled weights
                tw0[j] = h2f(f2h(C2L * W_hh[(cb + 0) * H + k]));
                tw1[j] = h2f(f2h(C2L * W_hh[(cb + 1) * H + k]));
                tw2[j] = h2f(f2h(C2L * W_hh[(cb + 2) * H + k]));
                tw3[j] = h2f(f2h(C2L * W_hh[(cb + 3) * H + k]));
            }
        }
        if (lane < 4) {
            const int c = cb + lane;
            twx0 = C2L * W_ih[c * 2];
            twx1 = C2L * W_ih[c * 2 + 1];
            tbA  = C2L * (b_ih[c] + b_hh[c]);
        }
    }

    // --- head constants (drain path): lane covers cols 4*lane..+3 ---
    f4v wo = {0.f, 0.f, 0.f, 0.f};
    if (c4 + 3 < H) wo = *(const f4v*)(W_out + c4);   // pads: wo = 0
    const float bo = b_out[0];

    __syncthreads();

    float* const op = out + b;
    const unsigned short* const aptr = &ring[0][(m == 1) ? 1 : 0][8 * q];

    // drain output tout (slot static): 2 b64 reads + DPP-only reduce.
    auto drain = [&](int slot, int tout) {
        float v = 0.f;
        if (lane < 56) {   // cols 0..223; pads are 0 and wo=0 there
            const s4v hv = *(const s4v*)(&ring[slot][0][0] + c4);
            const s4v lv = *(const s4v*)(&ring[slot][1][0] + c4);
            v = (h2f((unsigned short)hv[0]) + h2f((unsigned short)lv[0])) * wo[0]
              + (h2f((unsigned short)hv[1]) + h2f((unsigned short)lv[1])) * wo[1]
              + (h2f((unsigned short)hv[2]) + h2f((unsigned short)lv[2])) * wo[2]
              + (h2f((unsigned short)hv[3]) + h2f((unsigned short)lv[3])) * wo[3];
        }
        v = dpp_add<0xB1>(v);    // quad_perm(1,0,3,2)
        v = dpp_add<0x4E>(v);    // quad_perm(2,3,0,1)
        v = dpp_add<0x141>(v);   // row_half_mirror
        v = dpp_add<0x140>(v);   // row_mirror  -> each lane: its row16 sum
        const float r1 = rlane(v, 16);
        const float r2 = rlane(v, 32);
        const float r3 = rlane(v, 48);
        if (lane == 0) obuf[tout & 127] = ((v + r1) + (r2 + r3)) + bo;
    };

    for (int t8 = 0; t8 < T / RS; ++t8) {
        f4v xv0 = {0.f, 0.f, 0.f, 0.f};
        f4v xv1 = {0.f, 0.f, 0.f, 0.f};
#pragma unroll
        for (int rp = 0; rp < RS; ++rp) {
            const int t  = 8 * t8 + rp;
            const int sr = (rp + RS - 1) & (RS - 1);   // static read slot

            if (hasT || isTail) {
                if (rp == 0) {          // x for steps rp=0..3
                    xv0 = *(const f4v*)(xs + 16 * t8);
                    xv1 = *(const f4v*)(xs + 16 * t8 + 4);
                } else if (rp == 4) {   // x for steps rp=4..7
                    xv0 = *(const f4v*)(xs + 16 * t8 + 8);
                    xv1 = *(const f4v*)(xs + 16 * t8 + 12);
                }
            }
            const int r2i = rp & 3;  // static register picks
            const float x0 = (r2i == 0) ? xv0[0] : (r2i == 1) ? xv0[2]
                           : (r2i == 2) ? xv1[0] : xv1[2];
            const float x1 = (r2i == 0) ? xv0[1] : (r2i == 1) ? xv0[3]
                           : (r2i == 2) ? xv1[1] : xv1[3];

            if (hasT) {
                const float xterm = fmaf(x0, wxA0, fmaf(x1, wxA1, bA));

                // A: row0 h_hi, row1 h_lo; vaddr invariant, slot static.
                const unsigned short* ap = aptr + sr * 448;
                const s8v A0 = *(const s8v*)(ap);
                const s8v A1 = *(const s8v*)(ap + 32);
                const s8v A2 = *(const s8v*)(ap + 64);
                const s8v A3 = *(const s8v*)(ap + 96);
                const s8v A4 = *(const s8v*)(ap + 128);
                const s8v A5 = *(const s8v*)(ap + 160);
                const s8v A6 = *(const s8v*)(ap + 192);

                // 4 chains, dep depth <= 2 (R19 schedule)
                f4v u0 = {0.f, 0.f, 0.f, 0.f};
                f4v u1 = {0.f, 0.f, 0.f, 0.f};
                f4v u2 = {0.f, 0.f, 0.f, 0.f};
                f4v u3 = {0.f, 0.f, 0.f, 0.f};
                u0 = __builtin_amdgcn_mfma_f32_16x16x32_f16(A0, BA[0], u0, 0, 0, 0);
                u1 = __builtin_amdgcn_mfma_f32_16x16x32_f16(A2, BA[2], u1, 0, 0, 0);
                u2 = __builtin_amdgcn_mfma_f32_16x16x32_f16(A4, BA[4], u2, 0, 0, 0);
                u3 = __builtin_amdgcn_mfma_f32_16x16x32_f16(A6, BA[6], u3, 0, 0, 0);
                u0 = __builtin_amdgcn_mfma_f32_16x16x32_f16(A1, BA[1], u0, 0, 0, 0);
                u1 = __builtin_amdgcn_mfma_f32_16x16x32_f16(A3, BA[3], u1, 0, 0, 0);
                u2 = __builtin_amdgcn_mfma_f32_16x16x32_f16(A5, BA[5], u2, 0, 0, 0);

                if (q == 0) {
                    const float y = ((u0[0] + u0[1]) + (u1[0] + u1[1]))
                                  + ((u2[0] + u2[1]) + (u3[0] + u3[1]));
                    const float pre = y + xterm;              // C2L * true-pre
                    const float e2  = __builtin_amdgcn_exp2f(pre);
                    const float th  = 1.f - 2.f / (e2 + 1.f); // tanh
                    const unsigned short hi = f2h(th);
                    (&ring[rp][0][0])[nA] = hi;
                    (&ring[rp][1][0])[nA] = f2h(th - h2f(hi));
                }
            } else if (isTail) {
                // cols cb..cb+3 via VALU dot: h = hi + lo, DPP butterfly.
                float v0 = 0.f, v1 = 0.f, v2 = 0.f, v3 = 0.f;
                if (lane < 56) {
                    const s4v hv = *(const s4v*)(&ring[sr][0][0] + c4);
                    const s4v lv = *(const s4v*)(&ring[sr][1][0] + c4);
#pragma unroll
                    for (int j = 0; j < 4; ++j) {
                        const float hs = h2f((unsigned short)hv[j])
                                       + h2f((unsigned short)lv[j]);
                        v0 = fmaf(hs, tw0[j], v0);
                        v1 = fmaf(hs, tw1[j], v1);
                        v2 = fmaf(hs, tw2[j], v2);
                        v3 = fmaf(hs, tw3[j], v3);
                    }
                }
                v0 = dpp_add<0xB1>(v0);  v1 = dpp_add<0xB1>(v1);
                v2 = dpp_add<0xB1>(v2);  v3 = dpp_add<0xB1>(v3);
                v0 = dpp_add<0x4E>(v0);  v1 = dpp_add<0x4E>(v1);
                v2 = dpp_add<0x4E>(v2);  v3 = dpp_add<0x4E>(v3);
                v0 = dpp_add<0x141>(v0); v1 = dpp_add<0x141>(v1);
                v2 = dpp_add<0x141>(v2); v3 = dpp_add<0x141>(v3);
                v0 = dpp_add<0x140>(v0); v1 = dpp_add<0x140>(v1);
                v2 = dpp_add<0x140>(v2); v3 = dpp_add<0x140>(v3);
                const float t0 = ((v0 + rlane(v0, 16)) + (rlane(v0, 32) + rlane(v0, 48)));
                const float t1 = ((v1 + rlane(v1, 16)) + (rlane(v1, 32) + rlane(v1, 48)));
                const float t2 = ((v2 + rlane(v2, 16)) + (rlane(v2, 32) + rlane(v2, 48)));
                const float t3 = ((v3 + rlane(v3, 16)) + (rlane(v3, 32) + rlane(v3, 48)));
                if (lane < 4) {
                    const float ytot = (lane == 0) ? t0 : (lane == 1) ? t1
                                     : (lane == 2) ? t2 : t3;
                    const float pre = ytot + fmaf(x0, twx0, fmaf(x1, twx1, tbA));
                    const float e2  = __builtin_amdgcn_exp2f(pre);
                    const float th  = 1.f - 2.f / (e2 + 1.f);
                    const unsigned short hi = f2h(th);
                    const int c = 192 + 4 * (w - 14) + lane;
                    (&ring[rp][0][0])[c] = hi;
                    (&ring[rp][1][0])[c] = f2h(th - h2f(hi));
                }
            } else if (w == 12 + (rp & 1)) {
                // drain output t-2 (slot (rp+6)&7, static): written 2 steps
                // ago, rewritten at t+6 -> stable. w12: even t, w13: odd t.
                if (t8 > 0 || rp >= 2) drain((rp + 6) & (RS - 1), t - 2);
            } else if (w == 13) {
                // rp even here (w13 drains odd rp). Flush at rp==0.
                if (rp == 0 && (t8 & 7) == 2 && t8 >= 10) {
                    const int cc = (t8 - 10) >> 3;            // 0..30
                    const float val = obuf[((cc & 1) << 6) | lane];
                    op[(size_t)(64 * cc + lane) * B] = val;
                }
            }
            __syncthreads();
        }
    }

    // --- tail: outputs 2046,2047 undrained; then flush chunk 31 ---
    if (w == 12) drain(6, 2046);
    if (w == 13) drain(7, 2047);
    __syncthreads();
    if (w == 15) {
        const float val = obuf[64 | lane];   // outputs 1984..2047
        op[(size_t)(1984 + lane) * B] = val;
    }
}

extern "C" void kernel_launch(void* const* d_in, const int* in_sizes, int n_in,
                              void* d_out, int out_size, void* d_ws, size_t ws_size,
                              hipStream_t stream) {
    const float* x     = (const float*)d_in[0];
    const float* W_ih  = (const float*)d_in[1];
    const float* W_hh  = (const float*)d_in[2];
    const float* b_ih  = (const float*)d_in[3];
    const float* b_hh  = (const float*)d_in[4];
    const float* W_out = (const float*)d_in[5];
    const float* b_out = (const float*)d_in[6];
    float* out = (float*)d_out;

    rnn_fused<<<B, NTHR, 0, stream>>>(x, W_ih, W_hh, b_ih, b_hh, W_out, b_out, out);
}

// Round 12
// 942.906 us; speedup vs baseline: 1.4084x; 1.4084x over previous
//
#include <hip/hip_runtime.h>
#include <hip/hip_fp16.h>

// RNN_16492674416646: h_t = tanh(x_t W_ih^T + b_ih + b_hh + h_{t-1} W_hh^T),
// out_t = h_t W_out^T + b_out. T=2048, B=128, IN=2, H=200, OUT=1, fp32.
//
// R25 = R19 (best: 1010 us) + serial-epilogue shortening ONLY.
// Falsified to date: LDS-read count (R14/R22), LDS bandwidth (R14: masked
// reads null; R22: half the bytes, slower), MFMA count (R21/R23), occupancy
// cut (R15), drain offload onto long-path waves (R16/R23), setprio (R20).
// Budget at correct per-instr costs (16x16x32 mfma ~5cy): MFMA 140cy/SIMD,
// VALU ~310cy/SIMD, LDS ~300-450cy/CU -- all far under the 1183cy step.
// Residual = correlated waits (phase-locked barrier + ds-return window)
// + the q==0 serial epilogue. This round attacks the latter:
//  1. IEEE divide (div_scale/fmas/fixup ~10 ops) -> v_rcp_f32 + fmaf:
//     th = fmaf(-2, rcp(e2+1), 1). rcp err <= 1ulp -> th err ~1e-7.
//  2. C2L = 2*log2(e) folded into BA/wx/bA -> exp2(pre) direct (kills the
//     serial 2*pre mul; carried by R21/R22 with absmax unchanged).
//  3. x-selects + xterm sunk into the q==0 branch (-~8 issue slots/wave).
// Everything else bit-identical to R19: 13 tile-waves (7 MFMA, 4 chains),
// w13/w14 DPP-only drain (2-stale), w15 flush (64 outs/64 steps), x8
// unroll (static slots), 1 barrier/step, 2 b16 ring writes.
// absmax expected unchanged: 0.0078125 < 0.029.

typedef short s8v __attribute__((ext_vector_type(8)));   // 8 x fp16 bits
typedef short s4v __attribute__((ext_vector_type(4)));   // 4 x fp16 bits
typedef float f4v __attribute__((ext_vector_type(4)));

static constexpr int T = 2048;
static constexpr int B = 128;
static constexpr int H = 200;
static constexpr int NTHR = 1024;  // 16 waves
static constexpr int NT  = 13;     // n-tiles of 16 (208 >= 200)
static constexpr int KT  = 7;      // k-tiles of 32 (224 padded)
static constexpr int HP  = 224;    // padded H
static constexpr int RS  = 8;      // ring slots; T % RS == 0
static constexpr float C2L = 2.8853900817779268f;  // 2*log2(e)

__device__ __forceinline__ unsigned short f2h(float f) {
    const __half h = __float2half_rn(f);
    return *(const unsigned short*)&h;
}
__device__ __forceinline__ float h2f(unsigned short u) {
    const __half h = *(const __half*)&u;
    return __half2float(h);
}
// VALU-only cross-lane add (DPP); CTRL is a compile-time literal.
template <int CTRL>
__device__ __forceinline__ float dpp_add(float v) {
    const int i = __builtin_bit_cast(int, v);
    const int p = __builtin_amdgcn_update_dpp(0, i, CTRL, 0xF, 0xF, false);
    return v + __builtin_bit_cast(float, p);
}
__device__ __forceinline__ float rlane(float v, int l) {
    return __builtin_bit_cast(float,
        __builtin_amdgcn_readlane(__builtin_bit_cast(int, v), l));
}

__global__ __attribute__((amdgpu_flat_work_group_size(NTHR, NTHR),
                          amdgpu_waves_per_eu(4, 4)))
void rnn_fused(const float* __restrict__ x,     // [T,B,2]
               const float* __restrict__ W_ih,  // [H,2]
               const float* __restrict__ W_hh,  // [H,H]
               const float* __restrict__ b_ih,  // [H]
               const float* __restrict__ b_hh,  // [H]
               const float* __restrict__ W_out, // [1,H]
               const float* __restrict__ b_out, // [1]
               float* __restrict__ out)         // [T,B]
{
    const int b    = blockIdx.x;
    const int tid  = threadIdx.x;
    const int w    = tid >> 6;       // wave id 0..15
    const int lane = tid & 63;
    const int m    = lane & 15;      // A-row sel / B-col / D-col
    const int q    = lane >> 4;      // k-quad

    const bool hasT = (w < NT);      // 13 tile waves; 13/14 drain; 15 flush
    const int  nA   = 16 * w + m;
    const bool colv = hasT && (nA < H);

    __shared__ __align__(16) unsigned short ring[RS][2][HP];  // 7 KiB
    __shared__ __align__(16) float xs[2 * T];                 // 16 KiB
    __shared__ __align__(16) float obuf[128];                 // out staging

    for (int i = tid; i < RS * 2 * HP; i += NTHR) (&ring[0][0][0])[i] = 0;
    for (int idx = tid; idx < T; idx += NTHR) {
        const float2 v = *(const float2*)(x + (size_t)idx * (B * 2) + 2 * b);
        xs[2 * idx] = v.x; xs[2 * idx + 1] = v.y;
    }

    // --- loop-invariant B-fragment (fp16), C2L-scaled ---
    s8v BA[KT];
#pragma unroll
    for (int kt = 0; kt < KT; ++kt) {
        s8v ba{};
        if (colv) {
#pragma unroll
            for (int j = 0; j < 8; ++j) {
                const int ks = 32 * kt + 8 * q + j;
                ba[j] = (short)((ks < H) ? f2h(C2L * W_hh[nA * H + ks])
                                         : (unsigned short)0);
            }
        }
        BA[kt] = ba;
    }

    // --- epilogue constants (q==0 lanes of tile waves own col nA),
    //     C2L-scaled ---
    const float wxA0 = colv ? (C2L * W_ih[nA * 2])     : 0.f;
    const float wxA1 = colv ? (C2L * W_ih[nA * 2 + 1]) : 0.f;
    const float bA   = colv ? (C2L * (b_ih[nA] + b_hh[nA])) : 0.f;

    // --- head constants (drain path): lane covers cols 4*lane..+3 ---
    const int c4 = 4 * lane;
    f4v wo = {0.f, 0.f, 0.f, 0.f};
    if (c4 + 3 < H) wo = *(const f4v*)(W_out + c4);   // pads: wo = 0
    const float bo = b_out[0];

    __syncthreads();

    float* const op = out + b;
    const unsigned short* const aptr = &ring[0][(m == 1) ? 1 : 0][8 * q];

    // drain output tout (slot static): 2 b64 reads + DPP-only reduce.
    auto drain = [&](int slot, int tout) {
        float v = 0.f;
        if (lane < 56) {   // cols 0..223; pads are 0 and wo=0 there
            const s4v hv = *(const s4v*)(&ring[slot][0][0] + c4);
            const s4v lv = *(const s4v*)(&ring[slot][1][0] + c4);
            v = (h2f((unsigned short)hv[0]) + h2f((unsigned short)lv[0])) * wo[0]
              + (h2f((unsigned short)hv[1]) + h2f((unsigned short)lv[1])) * wo[1]
              + (h2f((unsigned short)hv[2]) + h2f((unsigned short)lv[2])) * wo[2]
              + (h2f((unsigned short)hv[3]) + h2f((unsigned short)lv[3])) * wo[3];
        }
        v = dpp_add<0xB1>(v);    // quad_perm(1,0,3,2)
        v = dpp_add<0x4E>(v);    // quad_perm(2,3,0,1)
        v = dpp_add<0x141>(v);   // row_half_mirror
        v = dpp_add<0x140>(v);   // row_mirror  -> each lane: its row16 sum
        const float r1 = rlane(v, 16);
        const float r2 = rlane(v, 32);
        const float r3 = rlane(v, 48);
        if (lane == 0) obuf[tout & 127] = ((v + r1) + (r2 + r3)) + bo;
    };

    for (int t8 = 0; t8 < T / RS; ++t8) {
        f4v xv0 = {0.f, 0.f, 0.f, 0.f};
        f4v xv1 = {0.f, 0.f, 0.f, 0.f};
#pragma unroll
        for (int rp = 0; rp < RS; ++rp) {
            const int t  = 8 * t8 + rp;
            const int sr = (rp + RS - 1) & (RS - 1);   // static read slot

            if (hasT) {
                if (rp == 0) {          // x for steps rp=0..3
                    xv0 = *(const f4v*)(xs + 16 * t8);
                    xv1 = *(const f4v*)(xs + 16 * t8 + 4);
                } else if (rp == 4) {   // x for steps rp=4..7
                    xv0 = *(const f4v*)(xs + 16 * t8 + 8);
                    xv1 = *(const f4v*)(xs + 16 * t8 + 12);
                }

                // A: row0 h_hi, row1 h_lo; vaddr invariant, slot static.
                const unsigned short* ap = aptr + sr * 448;
                const s8v A0 = *(const s8v*)(ap);
                const s8v A1 = *(const s8v*)(ap + 32);
                const s8v A2 = *(const s8v*)(ap + 64);
                const s8v A3 = *(const s8v*)(ap + 96);
                const s8v A4 = *(const s8v*)(ap + 128);
                const s8v A5 = *(const s8v*)(ap + 160);
                const s8v A6 = *(const s8v*)(ap + 192);

                // 4 chains, dep depth <= 2 (R19 schedule)
                f4v u0 = {0.f, 0.f, 0.f, 0.f};
                f4v u1 = {0.f, 0.f, 0.f, 0.f};
                f4v u2 = {0.f, 0.f, 0.f, 0.f};
                f4v u3 = {0.f, 0.f, 0.f, 0.f};
                u0 = __builtin_amdgcn_mfma_f32_16x16x32_f16(A0, BA[0], u0, 0, 0, 0);
                u1 = __builtin_amdgcn_mfma_f32_16x16x32_f16(A2, BA[2], u1, 0, 0, 0);
                u2 = __builtin_amdgcn_mfma_f32_16x16x32_f16(A4, BA[4], u2, 0, 0, 0);
                u3 = __builtin_amdgcn_mfma_f32_16x16x32_f16(A6, BA[6], u3, 0, 0, 0);
                u0 = __builtin_amdgcn_mfma_f32_16x16x32_f16(A1, BA[1], u0, 0, 0, 0);
                u1 = __builtin_amdgcn_mfma_f32_16x16x32_f16(A3, BA[3], u1, 0, 0, 0);
                u2 = __builtin_amdgcn_mfma_f32_16x16x32_f16(A5, BA[5], u2, 0, 0, 0);

                if (q == 0 && nA < H) {
                    // x picks + xterm only on the 16 lanes that need them
                    const int r2i = rp & 3;  // static register picks
                    const float x0 = (r2i == 0) ? xv0[0] : (r2i == 1) ? xv0[2]
                                   : (r2i == 2) ? xv1[0] : xv1[2];
                    const float x1 = (r2i == 0) ? xv0[1] : (r2i == 1) ? xv0[3]
                                   : (r2i == 2) ? xv1[1] : xv1[3];
                    const float xterm = fmaf(x0, wxA0, fmaf(x1, wxA1, bA));
                    const float y = ((u0[0] + u0[1]) + (u1[0] + u1[1]))
                                  + ((u2[0] + u2[1]) + (u3[0] + u3[1]));
                    const float pre = y + xterm;         // = C2L * true-pre
                    const float e2  = __builtin_amdgcn_exp2f(pre);
                    // tanh = 1 - 2/(e2+1), rcp form (err ~1e-7)
                    const float r   = __builtin_amdgcn_rcpf(e2 + 1.f);
                    const float th  = fmaf(-2.f, r, 1.f);
                    const unsigned short hi = f2h(th);
                    (&ring[rp][0][0])[nA] = hi;
                    (&ring[rp][1][0])[nA] = f2h(th - h2f(hi));
                }
            } else if (w == 13 + (rp & 1)) {
                // drain output t-2 (slot (rp+6)&7, static): written 2 steps
                // ago, rewritten at t+6 -> stable. w13: even t, w14: odd t.
                if (t8 > 0 || rp >= 2) drain((rp + 6) & (RS - 1), t - 2);
            } else if (w == 15) {
                // flush chunk cc = outputs [64cc, 64cc+64) once per 64
                // steps; last of chunk drained at step 64cc+65 <= t here.
                if (rp == 0 && (t8 & 7) == 2 && t8 >= 10) {
                    const int cc = (t8 - 10) >> 3;            // 0..30
                    const float val = obuf[((cc & 1) << 6) | lane];
                    op[(size_t)(64 * cc + lane) * B] = val;
                }
            }
            __syncthreads();
        }
    }

    // --- tail: outputs 2046,2047 undrained; then flush chunk 31 ---
    if (w == 13) drain(6, 2046);
    if (w == 14) drain(7, 2047);
    __syncthreads();
    if (w == 15) {
        const float val = obuf[64 | lane];   // outputs 1984..2047
        op[(size_t)(1984 + lane) * B] = val;
    }
}

extern "C" void kernel_launch(void* const* d_in, const int* in_sizes, int n_in,
                              void* d_out, int out_size, void* d_ws, size_t ws_size,
                              hipStream_t stream) {
    const float* x     = (const float*)d_in[0];
    const float* W_ih  = (const float*)d_in[1];
    const float* W_hh  = (const float*)d_in[2];
    const float* b_ih  = (const float*)d_in[3];
    const float* b_hh  = (const float*)d_in[4];
    const float* W_out = (const float*)d_in[5];
    const float* b_out = (const float*)d_in[6];
    float* out = (float*)d_out;

    rnn_fused<<<B, NTHR, 0, stream>>>(x, W_ih, W_hh, b_ih, b_hh, W_out, b_out, out);
}